// Round 3
// baseline (248.329 us; speedup 1.0000x reference)
//
#include <hip/hip_runtime.h>

// Problem constants
#define B_    4
#define S_    2048
#define HID_  1024
#define NO_   1024     // NH*HD
#define EPS_  1e-6f
#define M1_   (B_ * S_)   // 8192

typedef __attribute__((ext_vector_type(8))) short  short8;
typedef __attribute__((ext_vector_type(4))) float  f32x4;
typedef unsigned short ushort_t;

__device__ __forceinline__ unsigned short f2bf(float f) {
  union { float f; unsigned int u; } v; v.f = f;
  unsigned int r = v.u + 0x7FFFu + ((v.u >> 16) & 1u);  // RNE
  return (unsigned short)(r >> 16);
}
__device__ __forceinline__ unsigned pack2(float a, float b) {
  return (unsigned)f2bf(a) | ((unsigned)f2bf(b) << 16);
}

// async global->LDS, 16B per lane, dest = wave-uniform base + lane*16
typedef __attribute__((address_space(1))) const void GASV;
typedef __attribute__((address_space(3))) void LASV;
__device__ __forceinline__ void gld16(const void* g, void* l) {
  __builtin_amdgcn_global_load_lds((GASV*)g, (LASV*)l, 16, 0, 0);
}

// ---------------------------------------------------------------------------
// Fused prep (unchanged): WvT transpose+cvt | Hb=bf16(H) | Ab=bf16(A*inv)
// ---------------------------------------------------------------------------
__global__ __launch_bounds__(256) void k_prep(
    const float* __restrict__ Wv, ushort_t* __restrict__ WvT,
    const float* __restrict__ H,  ushort_t* __restrict__ Hb,
    const float* __restrict__ A,  ushort_t* __restrict__ Ab) {
  int id = blockIdx.x;
  if (id < 1024) {
    __shared__ float tile[32][33];
    int k0 = (id & 31) * 32;
    int n0 = (id >> 5) * 32;
    int tx = threadIdx.x & 31, ty = threadIdx.x >> 5;   // 32 x 8
    for (int i = ty; i < 32; i += 8)
      tile[i][tx] = Wv[(size_t)(k0 + i) * NO_ + n0 + tx];
    __syncthreads();
    for (int i = ty; i < 32; i += 8)
      WvT[(size_t)(n0 + i) * HID_ + k0 + tx] = f2bf(tile[tx][i]);
  } else if (id < 1024 + 8192) {
    size_t i = ((size_t)(id - 1024) * 256 + threadIdx.x) * 4;
    float4 v = *(const float4*)(H + i);
    uint2 p; p.x = pack2(v.x, v.y); p.y = pack2(v.z, v.w);
    *(uint2*)(Hb + i) = p;
  } else {
    int row  = (id - 9216) * 4 + (threadIdx.x >> 6);   // row = b*S + q
    int lane = threadIdx.x & 63;
    int q = row & 2047;
    int wend = ((q >> 7) + 1) << 7;
    const float* rp = A + (size_t)row * S_;
    float4 v[8];
    float s = 0.f;
#pragma unroll
    for (int i = 0; i < 8; i++) {
      int k = i * 256 + lane * 4;
      if (k < wend) {
        float4 t = *(const float4*)(rp + k);
        t.x = (k + 0 <= q) ? t.x : 0.f;
        t.y = (k + 1 <= q) ? t.y : 0.f;
        t.z = (k + 2 <= q) ? t.z : 0.f;
        t.w = (k + 3 <= q) ? t.w : 0.f;
        v[i] = t;
        s += t.x + t.y + t.z + t.w;
      }
    }
    for (int off = 1; off < 64; off <<= 1) s += __shfl_xor(s, off, 64);
    float inv = 1.0f / (EPS_ + s);
    ushort_t* op = Ab + (size_t)row * S_;
#pragma unroll
    for (int i = 0; i < 8; i++) {
      int k = i * 256 + lane * 4;
      if (k < wend) {
        uint2 p;
        p.x = pack2(v[i].x * inv, v[i].y * inv);
        p.y = pack2(v[i].z * inv, v[i].w * inv);
        *(uint2*)(op + k) = p;
      }
    }
  }
}

// ---------------------------------------------------------------------------
// GEMM 1: Vt[b][n][s] = bf16( sum_k WvT[n][k]*Hb[m][k] + bv[n] ), m=b*S+s.
// 256m x 128n tile, 512 threads / 8 waves (64x64 each), BK=32, depth-3 ring.
// XCD-engineered 1-D grid (assumes xcd = id%8): the 8 n-tiles sharing an
// Hb m-band co-locate on one XCD -> Hb band (512KB) + WvT (2MB) are L2-hits.
// ---------------------------------------------------------------------------
__global__ __launch_bounds__(512) void k_vt(
    const ushort_t* __restrict__ WvT, const ushort_t* __restrict__ Hb,
    const float* __restrict__ bv, ushort_t* __restrict__ Vt) {
  __shared__ __align__(16) ushort_t lds_a[4 * 128 * 32];  // 32 KB ring, n-rows
  __shared__ __align__(16) ushort_t lds_b[4 * 256 * 32];  // 64 KB ring, m-rows
  int id = blockIdx.x;
  int xcd  = id & 7;
  int mem  = id >> 3;
  int n0   = (mem & 7) * 128;
  int m0   = (xcd + (mem >> 3) * 8) * 256;   // m-tiles {xcd, xcd+8, xcd+16, xcd+24}
  int tid = threadIdx.x;
  int wave = tid >> 6, lane = tid & 63;
  int lq = lane >> 4, lm = lane & 15;
  int wm = wave >> 1, wn = wave & 1;        // wave tile: 64m x 64n

  int rr = lane >> 2;                       // 0..15 row within a 16-row issue
  int sc = (lane & 3) ^ ((rr >> 1) & 3);    // pre-swizzled 16B chunk (src side)
  const ushort_t* pa = WvT + (size_t)(n0 + wave * 16 + rr) * HID_ + sc * 8;
  const ushort_t* pb = Hb  + (size_t)(m0 + wave * 32 + rr) * HID_ + sc * 8;
  char* la = (char*)lds_a;
  char* lb = (char*)lds_b;
  char* la_w = la + wave * 1024;   // 16 n-rows * 64B per wave within a buffer
  char* lb_w = lb + wave * 2048;   // 32 m-rows * 64B
  int swz = (lm >> 1) & 3;
  int fo = (lq ^ swz) << 4;        // swizzled read offset (same involution)

  auto STAGE = [&](int tile) {
    char* da = la_w + (tile & 3) * 8192;
    char* db = lb_w + (tile & 3) * 16384;
    gld16(pa,             da);
    gld16(pb,             db);
    gld16(pb + 16 * HID_, db + 1024);
    pa += 32; pb += 32;
  };

  f32x4 acc[4][4];
  for (int i = 0; i < 4; i++) for (int j = 0; j < 4; j++) acc[i][j] = (f32x4)0.0f;

  const int iters = HID_ / 32;   // 32
  STAGE(0); STAGE(1); STAGE(2);
  for (int it = 0; it < iters; ++it) {
    int rem = iters - 1 - it;
    if (rem >= 3) { STAGE(it + 3); asm volatile("s_waitcnt vmcnt(9)" ::: "memory"); }
    else if (rem == 2) { asm volatile("s_waitcnt vmcnt(6)"  ::: "memory"); }
    else if (rem == 1) { asm volatile("s_waitcnt vmcnt(3)"  ::: "memory"); }
    else               { asm volatile("s_waitcnt vmcnt(0)"  ::: "memory"); }
    __builtin_amdgcn_s_barrier();
    const char* ra = la + (it & 3) * 8192;
    const char* rb = lb + (it & 3) * 16384;
    short8 af[4], bfr[4];
#pragma unroll
    for (int mi = 0; mi < 4; mi++)
      af[mi] = *(const short8*)(ra + (wn * 64 + mi * 16 + lm) * 64 + fo);
#pragma unroll
    for (int ni = 0; ni < 4; ni++)
      bfr[ni] = *(const short8*)(rb + (wm * 64 + ni * 16 + lm) * 64 + fo);
#pragma unroll
    for (int mi = 0; mi < 4; mi++)
#pragma unroll
      for (int ni = 0; ni < 4; ni++)
        acc[mi][ni] = __builtin_amdgcn_mfma_f32_16x16x32_bf16(af[mi], bfr[ni], acc[mi][ni], 0, 0, 0);
    asm volatile("" ::: "memory");
    __builtin_amdgcn_s_barrier();
  }
  for (int mi = 0; mi < 4; mi++) {
    for (int r = 0; r < 4; r++) {
      int n = n0 + wn * 64 + mi * 16 + lq * 4 + r;
      float bias = bv[n];
      for (int ni = 0; ni < 4; ni++) {
        int m = m0 + wm * 64 + ni * 16 + lm;
        int b = m >> 11;
        int s = m & 2047;
        Vt[((size_t)b * NO_ + n) * S_ + s] = f2bf(acc[mi][ni][r] + bias);
      }
    }
  }
}

// ---------------------------------------------------------------------------
// GEMM 2: out[b,q,n] = sum_k Ab[b,q,k] * Vt[b,n,k]   (inv pre-applied in Ab)
// 256q x 128n tile, 512 threads / 8 waves, BK=32, depth-3 ring.
// XCD-engineered grid: the 8 n-tiles sharing an Ab q-band co-locate per XCD
// (A multicast via L2); the 4 (b,t) groups on an XCD share one batch's Vt.
// Per-XCD K-work balanced exactly: t-sets {7,5,2,0} / {6,4,3,1}.
// ---------------------------------------------------------------------------
__global__ __launch_bounds__(512) void k_attn(
    const ushort_t* __restrict__ Ab, const ushort_t* __restrict__ Vt,
    float* __restrict__ out) {
  __shared__ __align__(16) ushort_t lds_a[4 * 256 * 32];  // 64 KB ring, q-rows
  __shared__ __align__(16) ushort_t lds_b[4 * 128 * 32];  // 32 KB ring, n-rows
  int id = blockIdx.x;
  int xcd  = id & 7;
  int mem  = id >> 3;
  int n0   = (mem & 7) * 128;
  int slot = mem >> 3;                       // 0..3
  int b    = xcd >> 1;
  int t    = (((xcd & 1) ? 0x1346 : 0x0257) >> (4 * slot)) & 15;
  int q0   = t * 256;
  int tid = threadIdx.x;
  int wave = tid >> 6, lane = tid & 63;
  int lq = lane >> 4, lm = lane & 15;
  int wq = wave >> 1, wn = wave & 1;        // wave tile: 64q x 64n

  int rr = lane >> 2;
  int sc = (lane & 3) ^ ((rr >> 1) & 3);
  const ushort_t* pa = Ab + ((size_t)(b * S_ + q0 + wave * 32 + rr)) * S_ + sc * 8;
  const ushort_t* pb = Vt + ((size_t)(b * NO_ + n0 + wave * 16 + rr)) * S_ + sc * 8;
  char* la = (char*)lds_a;
  char* lb = (char*)lds_b;
  char* la_w = la + wave * 2048;   // 32 q-rows per wave
  char* lb_w = lb + wave * 1024;   // 16 n-rows per wave
  int swz = (lm >> 1) & 3;
  int fo = (lq ^ swz) << 4;

  auto STAGE = [&](int tile) {
    char* da = la_w + (tile & 3) * 16384;
    char* db = lb_w + (tile & 3) * 8192;
    gld16(pa,           da);
    gld16(pa + 16 * S_, da + 1024);
    gld16(pb,           db);
    pa += 32; pb += 32;
  };

  f32x4 acc[4][4];
  for (int i = 0; i < 4; i++) for (int j = 0; j < 4; j++) acc[i][j] = (f32x4)0.0f;

  const int iters = 8 * (t + 1);        // K = 256*(t+1), BK=32; min 8 >= 3
  STAGE(0); STAGE(1); STAGE(2);
  for (int it = 0; it < iters; ++it) {
    int rem = iters - 1 - it;
    if (rem >= 3) { STAGE(it + 3); asm volatile("s_waitcnt vmcnt(9)" ::: "memory"); }
    else if (rem == 2) { asm volatile("s_waitcnt vmcnt(6)"  ::: "memory"); }
    else if (rem == 1) { asm volatile("s_waitcnt vmcnt(3)"  ::: "memory"); }
    else               { asm volatile("s_waitcnt vmcnt(0)"  ::: "memory"); }
    __builtin_amdgcn_s_barrier();
    const char* ra = la + (it & 3) * 16384;
    const char* rb = lb + (it & 3) * 8192;
    short8 af[4], bfr[4];
#pragma unroll
    for (int mi = 0; mi < 4; mi++)
      af[mi] = *(const short8*)(ra + (wq * 64 + mi * 16 + lm) * 64 + fo);
#pragma unroll
    for (int ni = 0; ni < 4; ni++)
      bfr[ni] = *(const short8*)(rb + (wn * 64 + ni * 16 + lm) * 64 + fo);
#pragma unroll
    for (int mi = 0; mi < 4; mi++)
#pragma unroll
      for (int ni = 0; ni < 4; ni++)
        acc[mi][ni] = __builtin_amdgcn_mfma_f32_16x16x32_bf16(af[mi], bfr[ni], acc[mi][ni], 0, 0, 0);
    asm volatile("" ::: "memory");
    __builtin_amdgcn_s_barrier();
  }
  for (int mi = 0; mi < 4; mi++) {
    for (int r = 0; r < 4; r++) {
      int q = q0 + wq * 64 + mi * 16 + lq * 4 + r;
      for (int ni = 0; ni < 4; ni++) {
        int n = n0 + wn * 64 + ni * 16 + lm;
        out[((size_t)(b * S_ + q)) * NO_ + n] = acc[mi][ni][r];
      }
    }
  }
}

// ---------------------------------------------------------------------------
extern "C" void kernel_launch(void* const* d_in, const int* in_sizes, int n_in,
                              void* d_out, int out_size, void* d_ws, size_t ws_size,
                              hipStream_t stream) {
  const float* H  = (const float*)d_in[0];   // [B,S,HID]
  const float* A  = (const float*)d_in[1];   // [B,S,S]
  const float* Wv = (const float*)d_in[3];   // [HID, NO]
  const float* bv = (const float*)d_in[4];   // [NO]
  float* out = (float*)d_out;

  char* ws = (char*)d_ws;
  ushort_t* WvT = (ushort_t*)ws;                                  //  2.0 MB
  ushort_t* Hb  = (ushort_t*)(ws + 2097152);                      // 16.8 MB
  ushort_t* Vt  = (ushort_t*)(ws + 2097152 + 16777216);           // 16.8 MB
  ushort_t* Abf = (ushort_t*)(ws + 2097152 + 2 * 16777216);       // 33.6 MB

  k_prep <<<1024 + 8192 + 2048, 256, 0, stream>>>(Wv, WvT, H, Hb, A, Abf);
  k_vt   <<<256, 512, 0, stream>>>(WvT, Hb, bv, Vt);
  k_attn <<<256, 512, 0, stream>>>(Abf, Vt, out);
}

// Round 4
// 239.428 us; speedup vs baseline: 1.0372x; 1.0372x over previous
//
#include <hip/hip_runtime.h>

// Problem constants
#define B_    4
#define S_    2048
#define HID_  1024
#define NO_   1024     // NH*HD
#define EPS_  1e-6f
#define M1_   (B_ * S_)   // 8192

typedef __attribute__((ext_vector_type(8))) short  short8;
typedef __attribute__((ext_vector_type(4))) float  f32x4;
typedef unsigned short ushort_t;

__device__ __forceinline__ unsigned short f2bf(float f) {
  union { float f; unsigned int u; } v; v.f = f;
  unsigned int r = v.u + 0x7FFFu + ((v.u >> 16) & 1u);  // RNE
  return (unsigned short)(r >> 16);
}
__device__ __forceinline__ unsigned pack2(float a, float b) {
  return (unsigned)f2bf(a) | ((unsigned)f2bf(b) << 16);
}

// async global->LDS, 16B per lane, dest = wave-uniform base + lane*16
typedef __attribute__((address_space(1))) const void GASV;
typedef __attribute__((address_space(3))) void LASV;
__device__ __forceinline__ void gld16(const void* g, void* l) {
  __builtin_amdgcn_global_load_lds((GASV*)g, (LASV*)l, 16, 0, 0);
}

// ---------------------------------------------------------------------------
// Fused prep (unchanged): WvT transpose+cvt | Hb=bf16(H) | Ab=bf16(A*inv)
// ---------------------------------------------------------------------------
__global__ __launch_bounds__(256) void k_prep(
    const float* __restrict__ Wv, ushort_t* __restrict__ WvT,
    const float* __restrict__ H,  ushort_t* __restrict__ Hb,
    const float* __restrict__ A,  ushort_t* __restrict__ Ab) {
  int id = blockIdx.x;
  if (id < 1024) {
    __shared__ float tile[32][33];
    int k0 = (id & 31) * 32;
    int n0 = (id >> 5) * 32;
    int tx = threadIdx.x & 31, ty = threadIdx.x >> 5;   // 32 x 8
    for (int i = ty; i < 32; i += 8)
      tile[i][tx] = Wv[(size_t)(k0 + i) * NO_ + n0 + tx];
    __syncthreads();
    for (int i = ty; i < 32; i += 8)
      WvT[(size_t)(n0 + i) * HID_ + k0 + tx] = f2bf(tile[tx][i]);
  } else if (id < 1024 + 8192) {
    size_t i = ((size_t)(id - 1024) * 256 + threadIdx.x) * 4;
    float4 v = *(const float4*)(H + i);
    uint2 p; p.x = pack2(v.x, v.y); p.y = pack2(v.z, v.w);
    *(uint2*)(Hb + i) = p;
  } else {
    int row  = (id - 9216) * 4 + (threadIdx.x >> 6);   // row = b*S + q
    int lane = threadIdx.x & 63;
    int q = row & 2047;
    int wend = ((q >> 7) + 1) << 7;
    const float* rp = A + (size_t)row * S_;
    float4 v[8];
    float s = 0.f;
#pragma unroll
    for (int i = 0; i < 8; i++) {
      int k = i * 256 + lane * 4;
      if (k < wend) {
        float4 t = *(const float4*)(rp + k);
        t.x = (k + 0 <= q) ? t.x : 0.f;
        t.y = (k + 1 <= q) ? t.y : 0.f;
        t.z = (k + 2 <= q) ? t.z : 0.f;
        t.w = (k + 3 <= q) ? t.w : 0.f;
        v[i] = t;
        s += t.x + t.y + t.z + t.w;
      }
    }
    for (int off = 1; off < 64; off <<= 1) s += __shfl_xor(s, off, 64);
    float inv = 1.0f / (EPS_ + s);
    ushort_t* op = Ab + (size_t)row * S_;
#pragma unroll
    for (int i = 0; i < 8; i++) {
      int k = i * 256 + lane * 4;
      if (k < wend) {
        uint2 p;
        p.x = pack2(v[i].x * inv, v[i].y * inv);
        p.y = pack2(v[i].z * inv, v[i].w * inv);
        *(uint2*)(op + k) = p;
      }
    }
  }
}

// ---------------------------------------------------------------------------
// GEMM 1: Vt[b][n][s] = bf16( sum_k WvT[n][k]*Hb[m][k] + bv[n] ), m=b*S+s.
// 128x128 tile, 4 waves, BK=32. 3-buffer LDS ring (48 KB -> 3 blocks/CU
// capacity, 2 co-resident), depth-2 counted vmcnt (8/4/0). XCD-grouped 1-D
// grid (id%8 -> xcd, verified by r3 FETCH drop): each XCD's 64 blocks share
// a 2 MB Hb m-band + 2 MB WvT = 4 MB L2 working set.
// ---------------------------------------------------------------------------
__global__ __launch_bounds__(256) void k_vt(
    const ushort_t* __restrict__ WvT, const ushort_t* __restrict__ Hb,
    const float* __restrict__ bv, ushort_t* __restrict__ Vt) {
  __shared__ __align__(16) ushort_t lds_a[3 * 128 * 32];  // 24 KB ring, n-rows
  __shared__ __align__(16) ushort_t lds_b[3 * 128 * 32];  // 24 KB ring, m-rows
  int id = blockIdx.x;
  int xcd = id & 7;
  int mem = id >> 3;                         // 0..63
  int n0  = (mem & 7) * 128;
  int m0  = (xcd * 8 + (mem >> 3)) * 128;    // per-XCD contiguous m-band
  int tid = threadIdx.x;
  int wave = tid >> 6, lane = tid & 63;
  int lq = lane >> 4, lm = lane & 15;
  int wr = wave >> 1, wc = wave & 1;

  int rr = lane >> 2;                      // 0..15 row within a 16-row issue
  int sc = (lane & 3) ^ ((rr >> 1) & 3);   // pre-swizzled 16B chunk (src side)
  const ushort_t* pa = WvT + (size_t)(n0 + wave * 32 + rr) * HID_ + sc * 8;
  const ushort_t* pb = Hb  + (size_t)(m0 + wave * 32 + rr) * HID_ + sc * 8;
  char* la = (char*)lds_a;
  char* lb = (char*)lds_b;
  char* la_w = la + wave * 2048;   // 32 rows * 64B per wave within a buffer
  char* lb_w = lb + wave * 2048;
  int swz = (lm >> 1) & 3;
  int fo = (lq ^ swz) << 4;        // swizzled read offset (same involution)

  auto STAGE = [&](int buf) {
    char* da = la_w + buf * 8192;
    char* db = lb_w + buf * 8192;
    gld16(pa,             da);
    gld16(pa + 16 * HID_, da + 1024);
    gld16(pb,             db);
    gld16(pb + 16 * HID_, db + 1024);
    pa += 32; pb += 32;
  };

  f32x4 acc[4][4];
  for (int i = 0; i < 4; i++) for (int j = 0; j < 4; j++) acc[i][j] = (f32x4)0.0f;

  const int iters = HID_ / 32;   // 32
  STAGE(0); STAGE(1);
  int rbuf = 0, wbuf = 2;
  for (int it = 0; it < iters; ++it) {
    int rem = iters - 1 - it;
    if (rem >= 2)      { STAGE(wbuf); asm volatile("s_waitcnt vmcnt(8)" ::: "memory"); }
    else if (rem == 1) { asm volatile("s_waitcnt vmcnt(4)" ::: "memory"); }
    else               { asm volatile("s_waitcnt vmcnt(0)" ::: "memory"); }
    __builtin_amdgcn_s_barrier();
    const char* ra = la + rbuf * 8192;
    const char* rb = lb + rbuf * 8192;
    short8 af[4], bfr[4];
#pragma unroll
    for (int mi = 0; mi < 4; mi++)
      af[mi] = *(const short8*)(ra + (wr * 64 + mi * 16 + lm) * 64 + fo);
#pragma unroll
    for (int ni = 0; ni < 4; ni++)
      bfr[ni] = *(const short8*)(rb + (wc * 64 + ni * 16 + lm) * 64 + fo);
    __builtin_amdgcn_s_setprio(1);
#pragma unroll
    for (int mi = 0; mi < 4; mi++)
#pragma unroll
      for (int ni = 0; ni < 4; ni++)
        acc[mi][ni] = __builtin_amdgcn_mfma_f32_16x16x32_bf16(af[mi], bfr[ni], acc[mi][ni], 0, 0, 0);
    __builtin_amdgcn_s_setprio(0);
    asm volatile("" ::: "memory");
    __builtin_amdgcn_s_barrier();
    rbuf = (rbuf == 2) ? 0 : rbuf + 1;
    wbuf = (wbuf == 2) ? 0 : wbuf + 1;
  }
  for (int mi = 0; mi < 4; mi++) {
    for (int r = 0; r < 4; r++) {
      int n = n0 + wr * 64 + mi * 16 + lq * 4 + r;
      float bias = bv[n];
      for (int ni = 0; ni < 4; ni++) {
        int m = m0 + wc * 64 + ni * 16 + lm;
        int b = m >> 11;
        int s = m & 2047;
        Vt[((size_t)b * NO_ + n) * S_ + s] = f2bf(acc[mi][ni][r] + bias);
      }
    }
  }
}

// ---------------------------------------------------------------------------
// GEMM 2: out[b,q,n] = sum_k Ab[b,q,k] * Vt[b,n,k]   (inv pre-applied in Ab)
// 128x128 tile, 4 waves, BK=32, 3-buffer ring, depth-2 counted vmcnt.
// grid (32, 16) = 512 blocks, 2 co-resident/CU (48 KB LDS). Complementary
// t-map: blocks id and id+256 (same CU under round-robin) get t and 15-t,
// so every CU runs exactly 68 K-iterations. Heavy tiles dispatch first.
// ---------------------------------------------------------------------------
__global__ __launch_bounds__(256) void k_attn(
    const ushort_t* __restrict__ Ab, const ushort_t* __restrict__ Vt,
    float* __restrict__ out) {
  __shared__ __align__(16) ushort_t lds_a[3 * 128 * 32];  // 24 KB ring, q-rows
  __shared__ __align__(16) ushort_t lds_b[3 * 128 * 32];  // 24 KB ring, n-rows
  int col = blockIdx.x;                 // 32 columns: (n-tile, b)
  int n0 = (col & 7) * 128;
  int b  = col >> 3;
  int y  = (int)blockIdx.y;
  int t  = (y < 8) ? (15 - y) : (y - 8);   // complementary pairing, heavy first
  int q0 = t * 128;
  int tid = threadIdx.x;
  int wave = tid >> 6, lane = tid & 63;
  int lq = lane >> 4, lm = lane & 15;
  int wr = wave >> 1, wc = wave & 1;

  int rr = lane >> 2;
  int sc = (lane & 3) ^ ((rr >> 1) & 3);
  const ushort_t* pa = Ab + ((size_t)(b * S_ + q0 + wave * 32 + rr)) * S_ + sc * 8;
  const ushort_t* pb = Vt + ((size_t)(b * NO_ + n0 + wave * 32 + rr)) * S_ + sc * 8;
  char* la = (char*)lds_a;
  char* lb = (char*)lds_b;
  char* la_w = la + wave * 2048;
  char* lb_w = lb + wave * 2048;
  int swz = (lm >> 1) & 3;
  int fo = (lq ^ swz) << 4;

  auto STAGE = [&](int buf) {
    char* da = la_w + buf * 8192;
    char* db = lb_w + buf * 8192;
    gld16(pa,           da);
    gld16(pa + 16 * S_, da + 1024);
    gld16(pb,           db);
    gld16(pb + 16 * S_, db + 1024);
    pa += 32; pb += 32;
  };

  f32x4 acc[4][4];
  for (int i = 0; i < 4; i++) for (int j = 0; j < 4; j++) acc[i][j] = (f32x4)0.0f;

  const int iters = 4 * t + 4;        // K = 128*(t+1), BK=32; min 4 >= 2
  STAGE(0); STAGE(1);
  int rbuf = 0, wbuf = 2;
  for (int it = 0; it < iters; ++it) {
    int rem = iters - 1 - it;
    if (rem >= 2)      { STAGE(wbuf); asm volatile("s_waitcnt vmcnt(8)" ::: "memory"); }
    else if (rem == 1) { asm volatile("s_waitcnt vmcnt(4)" ::: "memory"); }
    else               { asm volatile("s_waitcnt vmcnt(0)" ::: "memory"); }
    __builtin_amdgcn_s_barrier();
    const char* ra = la + rbuf * 8192;
    const char* rb = lb + rbuf * 8192;
    short8 af[4], bfr[4];
#pragma unroll
    for (int mi = 0; mi < 4; mi++)
      af[mi] = *(const short8*)(ra + (wr * 64 + mi * 16 + lm) * 64 + fo);
#pragma unroll
    for (int ni = 0; ni < 4; ni++)
      bfr[ni] = *(const short8*)(rb + (wc * 64 + ni * 16 + lm) * 64 + fo);
    __builtin_amdgcn_s_setprio(1);
#pragma unroll
    for (int mi = 0; mi < 4; mi++)
#pragma unroll
      for (int ni = 0; ni < 4; ni++)
        acc[mi][ni] = __builtin_amdgcn_mfma_f32_16x16x32_bf16(af[mi], bfr[ni], acc[mi][ni], 0, 0, 0);
    __builtin_amdgcn_s_setprio(0);
    asm volatile("" ::: "memory");
    __builtin_amdgcn_s_barrier();
    rbuf = (rbuf == 2) ? 0 : rbuf + 1;
    wbuf = (wbuf == 2) ? 0 : wbuf + 1;
  }
  for (int mi = 0; mi < 4; mi++) {
    for (int r = 0; r < 4; r++) {
      int q = q0 + wr * 64 + mi * 16 + lq * 4 + r;
      for (int ni = 0; ni < 4; ni++) {
        int n = n0 + wc * 64 + ni * 16 + lm;
        out[((size_t)(b * S_ + q)) * NO_ + n] = acc[mi][ni][r];
      }
    }
  }
}

// ---------------------------------------------------------------------------
extern "C" void kernel_launch(void* const* d_in, const int* in_sizes, int n_in,
                              void* d_out, int out_size, void* d_ws, size_t ws_size,
                              hipStream_t stream) {
  const float* H  = (const float*)d_in[0];   // [B,S,HID]
  const float* A  = (const float*)d_in[1];   // [B,S,S]
  const float* Wv = (const float*)d_in[3];   // [HID, NO]
  const float* bv = (const float*)d_in[4];   // [NO]
  float* out = (float*)d_out;

  char* ws = (char*)d_ws;
  ushort_t* WvT = (ushort_t*)ws;                                  //  2.0 MB
  ushort_t* Hb  = (ushort_t*)(ws + 2097152);                      // 16.8 MB
  ushort_t* Vt  = (ushort_t*)(ws + 2097152 + 16777216);           // 16.8 MB
  ushort_t* Abf = (ushort_t*)(ws + 2097152 + 2 * 16777216);       // 33.6 MB

  k_prep <<<1024 + 8192 + 2048, 256, 0, stream>>>(Wv, WvT, H, Hb, A, Abf);
  k_vt   <<<512, 256, 0, stream>>>(WvT, Hb, bv, Vt);
  k_attn <<<dim3(32, 16), 256, 0, stream>>>(Abf, Vt, out);
}

// Round 6
// 214.271 us; speedup vs baseline: 1.1589x; 1.1174x over previous
//
#include <hip/hip_runtime.h>

// Problem constants
#define B_    4
#define S_    2048
#define HID_  1024
#define NO_   1024     // NH*HD
#define EPS_  1e-6f
#define M1_   (B_ * S_)   // 8192

typedef __attribute__((ext_vector_type(8))) short  short8;
typedef __attribute__((ext_vector_type(4))) float  f32x4;
typedef unsigned short ushort_t;

__device__ __forceinline__ unsigned short f2bf(float f) {
  union { float f; unsigned int u; } v; v.f = f;
  unsigned int r = v.u + 0x7FFFu + ((v.u >> 16) & 1u);  // RNE
  return (unsigned short)(r >> 16);
}
__device__ __forceinline__ unsigned pack2(float a, float b) {
  return (unsigned)f2bf(a) | ((unsigned)f2bf(b) << 16);
}

// async global->LDS, 16B per lane, dest = wave-uniform base + lane*16
typedef __attribute__((address_space(1))) const void GASV;
typedef __attribute__((address_space(3))) void LASV;
__device__ __forceinline__ void gld16(const void* g, void* l) {
  __builtin_amdgcn_global_load_lds((GASV*)g, (LASV*)l, 16, 0, 0);
}

// ---------------------------------------------------------------------------
// Fused prep (unchanged): WvT transpose+cvt | Hb=bf16(H) | Ab=bf16(A*inv)
// ---------------------------------------------------------------------------
__global__ __launch_bounds__(256) void k_prep(
    const float* __restrict__ Wv, ushort_t* __restrict__ WvT,
    const float* __restrict__ H,  ushort_t* __restrict__ Hb,
    const float* __restrict__ A,  ushort_t* __restrict__ Ab) {
  int id = blockIdx.x;
  if (id < 1024) {
    __shared__ float tile[32][33];
    int k0 = (id & 31) * 32;
    int n0 = (id >> 5) * 32;
    int tx = threadIdx.x & 31, ty = threadIdx.x >> 5;   // 32 x 8
    for (int i = ty; i < 32; i += 8)
      tile[i][tx] = Wv[(size_t)(k0 + i) * NO_ + n0 + tx];
    __syncthreads();
    for (int i = ty; i < 32; i += 8)
      WvT[(size_t)(n0 + i) * HID_ + k0 + tx] = f2bf(tile[tx][i]);
  } else if (id < 1024 + 8192) {
    size_t i = ((size_t)(id - 1024) * 256 + threadIdx.x) * 4;
    float4 v = *(const float4*)(H + i);
    uint2 p; p.x = pack2(v.x, v.y); p.y = pack2(v.z, v.w);
    *(uint2*)(Hb + i) = p;
  } else {
    int row  = (id - 9216) * 4 + (threadIdx.x >> 6);   // row = b*S + q
    int lane = threadIdx.x & 63;
    int q = row & 2047;
    int wend = ((q >> 7) + 1) << 7;
    const float* rp = A + (size_t)row * S_;
    float4 v[8];
    float s = 0.f;
#pragma unroll
    for (int i = 0; i < 8; i++) {
      int k = i * 256 + lane * 4;
      if (k < wend) {
        float4 t = *(const float4*)(rp + k);
        t.x = (k + 0 <= q) ? t.x : 0.f;
        t.y = (k + 1 <= q) ? t.y : 0.f;
        t.z = (k + 2 <= q) ? t.z : 0.f;
        t.w = (k + 3 <= q) ? t.w : 0.f;
        v[i] = t;
        s += t.x + t.y + t.z + t.w;
      }
    }
    for (int off = 1; off < 64; off <<= 1) s += __shfl_xor(s, off, 64);
    float inv = 1.0f / (EPS_ + s);
    ushort_t* op = Ab + (size_t)row * S_;
#pragma unroll
    for (int i = 0; i < 8; i++) {
      int k = i * 256 + lane * 4;
      if (k < wend) {
        uint2 p;
        p.x = pack2(v[i].x * inv, v[i].y * inv);
        p.y = pack2(v[i].z * inv, v[i].w * inv);
        *(uint2*)(op + k) = p;
      }
    }
  }
}

// ---------------------------------------------------------------------------
// GEMM 1: Vt[b][n][s] = bf16( sum_k WvT[n][k]*Hb[m][k] + bv[n] ), m=b*S+s.
// 128n x 128m tile, BK=64, 8 waves (each 64n x 32m), 3-buffer ring (96 KB,
// 1 block/CU), depth-2 counted vmcnt (4 gld16/wave/tile). 2 phases/K-step:
// {ds_read sub ∥ gld16 pair -> barrier -> 8 MFMA (setprio) -> barrier}.
// XCD-grouped 1-D grid (r4-verified mapping, FETCH -70%): per-XCD Hb m-band
// + WvT L2-resident. 512 blocks, 2 rounds/CU.
// ---------------------------------------------------------------------------
__global__ __launch_bounds__(512) void k_vt(
    const ushort_t* __restrict__ WvT, const ushort_t* __restrict__ Hb,
    const float* __restrict__ bv, ushort_t* __restrict__ Vt) {
  // per 32 KB buffer: A(n,128 rows) kh0 at 0, kh1 at 8192;
  //                   B(m,128 rows) kh0 at 16384, kh1 at 24576.
  __shared__ __align__(16) char lds[3 * 32768];
  int id  = blockIdx.x;
  int xcd = id & 7;
  int mem = id >> 3;                       // 0..63
  int n0  = (mem & 7) * 128;
  int m0  = (xcd * 8 + (mem >> 3)) * 128;  // per-XCD contiguous m-band
  int tid = threadIdx.x;
  int wave = tid >> 6, lane = tid & 63;
  int lq = lane >> 4, lm = lane & 15;
  int wq = wave >> 2, wn = wave & 3;       // wave tile: 64n x 32m

  int rr = lane >> 2;
  int sc = (lane & 3) ^ ((rr >> 1) & 3);
  int fo = (lq ^ ((lm >> 1) & 3)) << 4;
  const ushort_t* pa = WvT + (size_t)(n0 + wave * 16 + rr) * HID_ + sc * 8;
  const ushort_t* pb = Hb  + (size_t)(m0 + wave * 16 + rr) * HID_ + sc * 8;

  f32x4 acc[4][2];
  for (int i = 0; i < 4; i++) for (int j = 0; j < 2; j++) acc[i][j] = (f32x4)0.0f;

  const int N = 16;   // K-steps of 64

  // prologue: full stage of tiles 0,1 (4 gld16 each per wave)
#pragma unroll
  for (int tpre = 0; tpre < 2; ++tpre) {
    char* wb = lds + tpre * 32768;
    gld16(pa,      wb + wave * 1024);              // A kh0
    gld16(pa + 32, wb + 8192  + wave * 1024);      // A kh1
    gld16(pb,      wb + 16384 + wave * 1024);      // B kh0
    gld16(pb + 32, wb + 24576 + wave * 1024);      // B kh1
    pa += 64; pb += 64;
  }
  asm volatile("s_waitcnt vmcnt(4)" ::: "memory");
  __builtin_amdgcn_s_barrier();

  int rbuf = 0;
  for (int it = 0; it < N; ++it) {
    int wbuf = rbuf + 2; if (wbuf >= 3) wbuf -= 3;
    bool stg = (it + 2) < N;
    const char* ra = lds + rbuf * 32768;
    char* wb = lds + wbuf * 32768;
    short8 af[4], bf0, bf1;
    // ---- phase 0: kh=0
#pragma unroll
    for (int mi = 0; mi < 4; mi++)
      af[mi] = *(const short8*)(ra + (wq * 64 + mi * 16 + lm) * 64 + fo);
    bf0 = *(const short8*)(ra + 16384 + (wn * 32 +  0 + lm) * 64 + fo);
    bf1 = *(const short8*)(ra + 16384 + (wn * 32 + 16 + lm) * 64 + fo);
    if (stg) { gld16(pa, wb + wave * 1024); gld16(pb, wb + 16384 + wave * 1024); }
    __builtin_amdgcn_s_barrier();
    __builtin_amdgcn_s_setprio(1);
#pragma unroll
    for (int mi = 0; mi < 4; mi++) {
      acc[mi][0] = __builtin_amdgcn_mfma_f32_16x16x32_bf16(af[mi], bf0, acc[mi][0], 0, 0, 0);
      acc[mi][1] = __builtin_amdgcn_mfma_f32_16x16x32_bf16(af[mi], bf1, acc[mi][1], 0, 0, 0);
    }
    __builtin_amdgcn_s_setprio(0);
    __builtin_amdgcn_s_barrier();
    // ---- phase 1: kh=1
#pragma unroll
    for (int mi = 0; mi < 4; mi++)
      af[mi] = *(const short8*)(ra + 8192 + (wq * 64 + mi * 16 + lm) * 64 + fo);
    bf0 = *(const short8*)(ra + 24576 + (wn * 32 +  0 + lm) * 64 + fo);
    bf1 = *(const short8*)(ra + 24576 + (wn * 32 + 16 + lm) * 64 + fo);
    if (stg) { gld16(pa + 32, wb + 8192 + wave * 1024); gld16(pb + 32, wb + 24576 + wave * 1024); pa += 64; pb += 64; }
    __builtin_amdgcn_s_barrier();
    __builtin_amdgcn_s_setprio(1);
#pragma unroll
    for (int mi = 0; mi < 4; mi++) {
      acc[mi][0] = __builtin_amdgcn_mfma_f32_16x16x32_bf16(af[mi], bf0, acc[mi][0], 0, 0, 0);
      acc[mi][1] = __builtin_amdgcn_mfma_f32_16x16x32_bf16(af[mi], bf1, acc[mi][1], 0, 0, 0);
    }
    __builtin_amdgcn_s_setprio(0);
    if (it < N - 1) {
      if (it + 2 < N) asm volatile("s_waitcnt vmcnt(4)" ::: "memory");
      else            asm volatile("s_waitcnt vmcnt(0)" ::: "memory");
    }
    __builtin_amdgcn_s_barrier();
    rbuf = (rbuf == 2) ? 0 : rbuf + 1;
  }
  for (int mi = 0; mi < 4; mi++) {
    for (int r = 0; r < 4; r++) {
      int n = n0 + wq * 64 + mi * 16 + lq * 4 + r;
      float bias = bv[n];
      for (int ni = 0; ni < 2; ni++) {
        int m = m0 + wn * 32 + ni * 16 + lm;
        int b = m >> 11;
        int s = m & 2047;
        Vt[((size_t)b * NO_ + n) * S_ + s] = f2bf(acc[mi][ni][r] + bias);
      }
    }
  }
}

// ---------------------------------------------------------------------------
// GEMM 2: out[b,q,n] = sum_k Ab[b,q,k] * Vt[b,n,k]   (inv pre-applied in Ab)
// 128q x 128n tile, BK=64, 8 waves (each 64q x 32n), 3-buffer ring (96 KB,
// 1 block/CU), depth-2 counted vmcnt (4 gld16/wave/tile). 2 phases/K-step.
// Each block runs paired q-tiles (t=y, 15-y) -> uniform 34 K-steps.
// XCD-grouped: b = xcd/2, n-half = xcd&1 -> Ab/Vt panels shared via L2.
// ---------------------------------------------------------------------------
__global__ __launch_bounds__(512) void k_attn(
    const ushort_t* __restrict__ Ab, const ushort_t* __restrict__ Vt,
    float* __restrict__ out) {
  // per 32 KB buffer: A(q,128) kh0 at 0, kh1 at 8192;
  //                   B(n,128) kh0 at 16384, kh1 at 24576.
  __shared__ __align__(16) char lds[3 * 32768];
  int id  = blockIdx.x;
  int xcd = id & 7;
  int mem = id >> 3;                       // 0..31
  int b   = xcd >> 1;
  int n0  = ((xcd & 1) * 4 + (mem & 3)) * 128;
  int y   = mem >> 2;                      // 0..7
  int tid = threadIdx.x;
  int wave = tid >> 6, lane = tid & 63;
  int lq = lane >> 4, lm = lane & 15;
  int wq = wave >> 2, wn = wave & 3;       // wave tile: 64q x 32n

  int rr = lane >> 2;
  int sc = (lane & 3) ^ ((rr >> 1) & 3);
  int fo = (lq ^ ((lm >> 1) & 3)) << 4;
  const ushort_t* pb0 = Vt + (size_t)(b * NO_ + n0 + wave * 16 + rr) * S_ + sc * 8;

  for (int seg = 0; seg < 2; ++seg) {
    int t  = seg ? (15 - y) : y;
    int q0 = t * 128;
    const int N = 2 * (t + 1);             // K-steps of 64
    const ushort_t* pa = Ab + (size_t)(b * S_ + q0 + wave * 16 + rr) * S_ + sc * 8;
    const ushort_t* pb = pb0;

    f32x4 acc[4][2];
    for (int i = 0; i < 4; i++) for (int j = 0; j < 2; j++) acc[i][j] = (f32x4)0.0f;

    // prologue: full stage of tiles 0,1 (4 gld16 each per wave)
#pragma unroll
    for (int tpre = 0; tpre < 2; ++tpre) {
      char* wb = lds + tpre * 32768;
      gld16(pa,      wb + wave * 1024);              // A kh0
      gld16(pa + 32, wb + 8192  + wave * 1024);      // A kh1
      gld16(pb,      wb + 16384 + wave * 1024);      // B kh0
      gld16(pb + 32, wb + 24576 + wave * 1024);      // B kh1
      pa += 64; pb += 64;
    }
    asm volatile("s_waitcnt vmcnt(4)" ::: "memory");
    __builtin_amdgcn_s_barrier();

    int rbuf = 0;
    for (int it = 0; it < N; ++it) {
      int wbuf = rbuf + 2; if (wbuf >= 3) wbuf -= 3;
      bool stg = (it + 2) < N;
      const char* ra = lds + rbuf * 32768;
      char* wb = lds + wbuf * 32768;
      short8 af[4], bf0, bf1;
      // ---- phase 0: kh=0
#pragma unroll
      for (int mi = 0; mi < 4; mi++)
        af[mi] = *(const short8*)(ra + (wq * 64 + mi * 16 + lm) * 64 + fo);
      bf0 = *(const short8*)(ra + 16384 + (wn * 32 +  0 + lm) * 64 + fo);
      bf1 = *(const short8*)(ra + 16384 + (wn * 32 + 16 + lm) * 64 + fo);
      if (stg) { gld16(pa, wb + wave * 1024); gld16(pb, wb + 16384 + wave * 1024); }
      __builtin_amdgcn_s_barrier();
      __builtin_amdgcn_s_setprio(1);
#pragma unroll
      for (int mi = 0; mi < 4; mi++) {
        acc[mi][0] = __builtin_amdgcn_mfma_f32_16x16x32_bf16(af[mi], bf0, acc[mi][0], 0, 0, 0);
        acc[mi][1] = __builtin_amdgcn_mfma_f32_16x16x32_bf16(af[mi], bf1, acc[mi][1], 0, 0, 0);
      }
      __builtin_amdgcn_s_setprio(0);
      __builtin_amdgcn_s_barrier();
      // ---- phase 1: kh=1
#pragma unroll
      for (int mi = 0; mi < 4; mi++)
        af[mi] = *(const short8*)(ra + 8192 + (wq * 64 + mi * 16 + lm) * 64 + fo);
      bf0 = *(const short8*)(ra + 24576 + (wn * 32 +  0 + lm) * 64 + fo);
      bf1 = *(const short8*)(ra + 24576 + (wn * 32 + 16 + lm) * 64 + fo);
      if (stg) { gld16(pa + 32, wb + 8192 + wave * 1024); gld16(pb + 32, wb + 24576 + wave * 1024); pa += 64; pb += 64; }
      __builtin_amdgcn_s_barrier();
      __builtin_amdgcn_s_setprio(1);
#pragma unroll
      for (int mi = 0; mi < 4; mi++) {
        acc[mi][0] = __builtin_amdgcn_mfma_f32_16x16x32_bf16(af[mi], bf0, acc[mi][0], 0, 0, 0);
        acc[mi][1] = __builtin_amdgcn_mfma_f32_16x16x32_bf16(af[mi], bf1, acc[mi][1], 0, 0, 0);
      }
      __builtin_amdgcn_s_setprio(0);
      if (it < N - 1) {
        if (it + 2 < N) asm volatile("s_waitcnt vmcnt(4)" ::: "memory");
        else            asm volatile("s_waitcnt vmcnt(0)" ::: "memory");
      }
      __builtin_amdgcn_s_barrier();
      rbuf = (rbuf == 2) ? 0 : rbuf + 1;
    }
    // epilogue for this q-tile
    for (int mi = 0; mi < 4; mi++) {
      for (int r = 0; r < 4; r++) {
        int q = q0 + wq * 64 + mi * 16 + lq * 4 + r;
        for (int ni = 0; ni < 2; ni++) {
          int n = n0 + wn * 32 + ni * 16 + lm;
          out[((size_t)(b * S_ + q)) * NO_ + n] = acc[mi][ni][r];
        }
      }
    }
    // drain stores + any stray loads so next segment's counted waits are exact
    asm volatile("s_waitcnt vmcnt(0)" ::: "memory");
    __builtin_amdgcn_s_barrier();
  }
}

// ---------------------------------------------------------------------------
extern "C" void kernel_launch(void* const* d_in, const int* in_sizes, int n_in,
                              void* d_out, int out_size, void* d_ws, size_t ws_size,
                              hipStream_t stream) {
  const float* H  = (const float*)d_in[0];   // [B,S,HID]
  const float* A  = (const float*)d_in[1];   // [B,S,S]
  const float* Wv = (const float*)d_in[3];   // [HID, NO]
  const float* bv = (const float*)d_in[4];   // [NO]
  float* out = (float*)d_out;

  char* ws = (char*)d_ws;
  ushort_t* WvT = (ushort_t*)ws;                                  //  2.0 MB
  ushort_t* Hb  = (ushort_t*)(ws + 2097152);                      // 16.8 MB
  ushort_t* Vt  = (ushort_t*)(ws + 2097152 + 16777216);           // 16.8 MB
  ushort_t* Abf = (ushort_t*)(ws + 2097152 + 2 * 16777216);       // 33.6 MB

  k_prep <<<1024 + 8192 + 2048, 256, 0, stream>>>(Wv, WvT, H, Hb, A, Abf);
  k_vt   <<<512, 512, 0, stream>>>(WvT, Hb, bv, Vt);
  k_attn <<<256, 512, 0, stream>>>(Abf, Vt, out);
}